// Round 1
// baseline (33502.945 us; speedup 1.0000x reference)
//
#include <hip/hip_runtime.h>

#define TT 512
#define II 8
#define HH 32

__device__ __forceinline__ float rcpf_(float x) { return __builtin_amdgcn_rcpf(x); }
__device__ __forceinline__ float sigf_(float z) { return rcpf_(1.f + __expf(-z)); }
__device__ __forceinline__ float tanhf_(float z) {
  float a = fabsf(z);
  float e = __expf(-2.f * a);            // in (0,1], no overflow
  float th = (1.f - e) * rcpf_(1.f + e);
  return copysignf(th, z);
}

// One wave per block; 2 batch elements per block.
// Lane L owns gate rows rA=(L>>4)*32+(L&15) and rB=rA+16 of BOTH layers (weights in VGPRs).
// After the dot, lanes are re-mapped via LDS so lane T handles unit u=T&31, batch b=T>>5.
__global__ __launch_bounds__(64, 2) void lstm_fused(
    const float* __restrict__ X,
    const float* __restrict__ ln_g, const float* __restrict__ ln_b,
    const float* __restrict__ Wih0g, const float* __restrict__ Whh0g,
    const float* __restrict__ bih0, const float* __restrict__ bhh0,
    const float* __restrict__ Wih1g, const float* __restrict__ Whh1g,
    const float* __restrict__ bih1, const float* __restrict__ bhh1,
    const float* __restrict__ W1, const float* __restrict__ b1,
    const float* __restrict__ W2, const float* __restrict__ b2,
    float* __restrict__ out)
{
  __shared__ __align__(16) float xbuf[2][2][II];   // [t&1][b][i], LN'd x
  __shared__ __align__(16) float h1buf[2][HH];     // [b][u]
  __shared__ __align__(16) float h2buf[2][HH];     // [b][u]
  __shared__ __align__(16) float pre[4 * HH][2];   // [gate_row][b]

  const int lane = threadIdx.x;
  const int b0 = blockIdx.x * 2;

  const int gq = lane >> 4;        // gate 0..3 (i,f,g,o)
  const int uu = lane & 15;
  const int rA = gq * HH + uu;     // owned gate rows
  const int rB = rA + 16;
  const int u_t = lane & 31;       // elementwise mapping: unit
  const int b_t = lane >> 5;       // elementwise mapping: batch (0/1)

  // ---- weights -> registers (208 VGPRs), once ----
  float wih0[2][II], whh0[2][HH], wih1[2][HH], whh1[2][HH];
  float bias0[2], bias1[2];
  #pragma unroll
  for (int h = 0; h < 2; ++h) {
    const int r = h ? rB : rA;
    {
      const float4* p = (const float4*)(Wih0g + r * II);
      #pragma unroll
      for (int q = 0; q < II / 4; ++q) {
        float4 v = p[q];
        wih0[h][q*4+0]=v.x; wih0[h][q*4+1]=v.y; wih0[h][q*4+2]=v.z; wih0[h][q*4+3]=v.w;
      }
    }
    {
      const float4* p = (const float4*)(Whh0g + r * HH);
      #pragma unroll
      for (int q = 0; q < HH / 4; ++q) {
        float4 v = p[q];
        whh0[h][q*4+0]=v.x; whh0[h][q*4+1]=v.y; whh0[h][q*4+2]=v.z; whh0[h][q*4+3]=v.w;
      }
    }
    {
      const float4* p = (const float4*)(Wih1g + r * HH);
      #pragma unroll
      for (int q = 0; q < HH / 4; ++q) {
        float4 v = p[q];
        wih1[h][q*4+0]=v.x; wih1[h][q*4+1]=v.y; wih1[h][q*4+2]=v.z; wih1[h][q*4+3]=v.w;
      }
    }
    {
      const float4* p = (const float4*)(Whh1g + r * HH);
      #pragma unroll
      for (int q = 0; q < HH / 4; ++q) {
        float4 v = p[q];
        whh1[h][q*4+0]=v.x; whh1[h][q*4+1]=v.y; whh1[h][q*4+2]=v.z; whh1[h][q*4+3]=v.w;
      }
    }
    bias0[h] = bih0[r] + bhh0[r];
    bias1[h] = bih1[r] + bhh1[r];
  }

  const float lngv = ln_g[lane & 7];
  const float lnbv = ln_b[lane & 7];

  h1buf[b_t][u_t] = 0.f;
  h2buf[b_t][u_t] = 0.f;
  float c1 = 0.f, c2 = 0.f;

  for (int t = 0; t < TT; ++t) {
    const int tt = t & 1;

    // ---- stage x for (t, t+1) on even t: full 64B line per batch, LN fused ----
    if (tt == 0 && lane < 32) {
      const int bb = lane >> 4, ts = (lane >> 3) & 1, ii = lane & 7;
      float v = X[(size_t)(b0 + bb) * (TT * II) + (size_t)(t + ts) * II + ii];
      float s = v;
      s += __shfl_xor(s, 1); s += __shfl_xor(s, 2); s += __shfl_xor(s, 4);
      const float mu = s * 0.125f;
      const float d = v - mu;
      float q2 = d * d;
      q2 += __shfl_xor(q2, 1); q2 += __shfl_xor(q2, 2); q2 += __shfl_xor(q2, 4);
      const float inv = __builtin_amdgcn_rsqf(fmaf(q2, 0.125f, 1e-5f)); // rsqrt(var+eps)
      xbuf[ts][bb][ii] = fmaf(d * inv, lngv, lnbv);
    }
    __syncthreads();  // S1

    // ---- layer 0 dot: gates[row,b] = b0r + Wih0*xn + Whh0*h1 ----
    float acc[2][2];
    acc[0][0] = bias0[0]; acc[0][1] = bias0[0];
    acc[1][0] = bias0[1]; acc[1][1] = bias0[1];
    #pragma unroll
    for (int b = 0; b < 2; ++b) {
      const float4* xp = (const float4*)&xbuf[tt][b][0];
      #pragma unroll
      for (int q = 0; q < II / 4; ++q) {
        const float4 v = xp[q];
        #pragma unroll
        for (int h = 0; h < 2; ++h) {
          acc[h][b] = fmaf(wih0[h][q*4+0], v.x, acc[h][b]);
          acc[h][b] = fmaf(wih0[h][q*4+1], v.y, acc[h][b]);
          acc[h][b] = fmaf(wih0[h][q*4+2], v.z, acc[h][b]);
          acc[h][b] = fmaf(wih0[h][q*4+3], v.w, acc[h][b]);
        }
      }
      const float4* hp = (const float4*)&h1buf[b][0];
      #pragma unroll
      for (int q = 0; q < HH / 4; ++q) {
        const float4 v = hp[q];
        #pragma unroll
        for (int h = 0; h < 2; ++h) {
          acc[h][b] = fmaf(whh0[h][q*4+0], v.x, acc[h][b]);
          acc[h][b] = fmaf(whh0[h][q*4+1], v.y, acc[h][b]);
          acc[h][b] = fmaf(whh0[h][q*4+2], v.z, acc[h][b]);
          acc[h][b] = fmaf(whh0[h][q*4+3], v.w, acc[h][b]);
        }
      }
    }
    *(float2*)&pre[rA][0] = make_float2(acc[0][0], acc[0][1]);
    *(float2*)&pre[rB][0] = make_float2(acc[1][0], acc[1][1]);
    __syncthreads();  // S2

    // ---- layer 0 elementwise: lane = (u_t, b_t) ----
    {
      const float pi = pre[u_t][b_t];
      const float pf = pre[HH + u_t][b_t];
      const float pg = pre[2 * HH + u_t][b_t];
      const float po = pre[3 * HH + u_t][b_t];
      const float gi = sigf_(pi), gf = sigf_(pf), gg = tanhf_(pg), go = sigf_(po);
      c1 = fmaf(gf, c1, gi * gg);
      h1buf[b_t][u_t] = go * tanhf_(c1);
    }
    __syncthreads();  // S3

    // ---- layer 1 dot: gates = b1r + Wih1*h1 + Whh1*h2 ----
    acc[0][0] = bias1[0]; acc[0][1] = bias1[0];
    acc[1][0] = bias1[1]; acc[1][1] = bias1[1];
    #pragma unroll
    for (int b = 0; b < 2; ++b) {
      const float4* hp1 = (const float4*)&h1buf[b][0];
      #pragma unroll
      for (int q = 0; q < HH / 4; ++q) {
        const float4 v = hp1[q];
        #pragma unroll
        for (int h = 0; h < 2; ++h) {
          acc[h][b] = fmaf(wih1[h][q*4+0], v.x, acc[h][b]);
          acc[h][b] = fmaf(wih1[h][q*4+1], v.y, acc[h][b]);
          acc[h][b] = fmaf(wih1[h][q*4+2], v.z, acc[h][b]);
          acc[h][b] = fmaf(wih1[h][q*4+3], v.w, acc[h][b]);
        }
      }
      const float4* hp2 = (const float4*)&h2buf[b][0];
      #pragma unroll
      for (int q = 0; q < HH / 4; ++q) {
        const float4 v = hp2[q];
        #pragma unroll
        for (int h = 0; h < 2; ++h) {
          acc[h][b] = fmaf(whh1[h][q*4+0], v.x, acc[h][b]);
          acc[h][b] = fmaf(whh1[h][q*4+1], v.y, acc[h][b]);
          acc[h][b] = fmaf(whh1[h][q*4+2], v.z, acc[h][b]);
          acc[h][b] = fmaf(whh1[h][q*4+3], v.w, acc[h][b]);
        }
      }
    }
    *(float2*)&pre[rA][0] = make_float2(acc[0][0], acc[0][1]);
    *(float2*)&pre[rB][0] = make_float2(acc[1][0], acc[1][1]);
    __syncthreads();  // S4

    // ---- layer 1 elementwise ----
    {
      const float pi = pre[u_t][b_t];
      const float pf = pre[HH + u_t][b_t];
      const float pg = pre[2 * HH + u_t][b_t];
      const float po = pre[3 * HH + u_t][b_t];
      const float gi = sigf_(pi), gf = sigf_(pf), gg = tanhf_(pg), go = sigf_(po);
      c2 = fmaf(gf, c2, gi * gg);
      h2buf[b_t][u_t] = go * tanhf_(c2);
    }
    // next iteration's S1/S2/S3 order the h2buf write vs. next layer-1 reads
  }
  __syncthreads();

  // ---- head: out[b] = tanh(W2 @ relu(W1 @ h2 + b1) + b2) ----
  if (lane < 32) {
    const int j = lane & 15;   // F1 = 16
    const int b = lane >> 4;
    float a = b1[j];
    const float4* hp = (const float4*)&h2buf[b][0];
    const float4* wp = (const float4*)(W1 + j * HH);
    #pragma unroll
    for (int q = 0; q < HH / 4; ++q) {
      const float4 hv = hp[q];
      const float4 wv = wp[q];
      a = fmaf(wv.x, hv.x, a); a = fmaf(wv.y, hv.y, a);
      a = fmaf(wv.z, hv.z, a); a = fmaf(wv.w, hv.w, a);
    }
    float r = fmaxf(a, 0.f) * W2[j];
    r += __shfl_xor(r, 1);
    r += __shfl_xor(r, 2);
    r += __shfl_xor(r, 4);
    r += __shfl_xor(r, 8);
    if (j == 0) out[b0 + b] = tanhf_(r + b2[0]);
  }
}

extern "C" void kernel_launch(void* const* d_in, const int* in_sizes, int n_in,
                              void* d_out, int out_size, void* d_ws, size_t ws_size,
                              hipStream_t stream) {
  const float* X     = (const float*)d_in[0];
  const float* ln_g  = (const float*)d_in[1];
  const float* ln_b  = (const float*)d_in[2];
  const float* Wih0g = (const float*)d_in[3];
  const float* Whh0g = (const float*)d_in[4];
  const float* bih0  = (const float*)d_in[5];
  const float* bhh0  = (const float*)d_in[6];
  const float* Wih1g = (const float*)d_in[7];
  const float* Whh1g = (const float*)d_in[8];
  const float* bih1  = (const float*)d_in[9];
  const float* bhh1  = (const float*)d_in[10];
  const float* W1    = (const float*)d_in[11];
  const float* b1    = (const float*)d_in[12];
  const float* W2    = (const float*)d_in[13];
  const float* b2    = (const float*)d_in[14];
  float* out = (float*)d_out;

  const int Bn = in_sizes[0] / (TT * II);   // 8192
  dim3 grid(Bn / 2), block(64);
  hipLaunchKernelGGL(lstm_fused, grid, block, 0, stream,
                     X, ln_g, ln_b, Wih0g, Whh0g, bih0, bhh0,
                     Wih1g, Whh1g, bih1, bhh1, W1, b1, W2, b2, out);
}

// Round 2
// 5677.086 us; speedup vs baseline: 5.9014x; 5.9014x over previous
//
#include <hip/hip_runtime.h>

#define TT 512
#define II 8
#define HH 32

__device__ __forceinline__ float rcpf_(float x) { return __builtin_amdgcn_rcpf(x); }
__device__ __forceinline__ float sigf_(float z) { return rcpf_(1.f + __expf(-z)); }
__device__ __forceinline__ float tanhf_(float z) {
  float a = fabsf(z);
  float e = __expf(-2.f * a);            // in (0,1], no overflow
  float th = (1.f - e) * rcpf_(1.f + e);
  return copysignf(th, z);
}

// One wave per block; 2 batch elements per block. Single-wave workgroup:
// __syncthreads() costs only waitcnt (no cross-wave barrier).
// Lane L owns gate rows rA=(L>>4)*32+(L&15) and rB=rA+16 of BOTH layers.
// Weights stay in VGPRs (208 floats/lane) -- launch_bounds(64,1) gives the
// allocator a 512-VGPR budget so it has no reason to spill (round-1 failure:
// (64,2) capped at 128 VGPRs and spilled 107 floats/lane -> 57 GB HBM).
__global__ __launch_bounds__(64, 1) void lstm_fused(
    const float* __restrict__ X,
    const float* __restrict__ ln_g, const float* __restrict__ ln_b,
    const float* __restrict__ Wih0g, const float* __restrict__ Whh0g,
    const float* __restrict__ bih0, const float* __restrict__ bhh0,
    const float* __restrict__ Wih1g, const float* __restrict__ Whh1g,
    const float* __restrict__ bih1, const float* __restrict__ bhh1,
    const float* __restrict__ W1, const float* __restrict__ b1,
    const float* __restrict__ W2, const float* __restrict__ b2,
    float* __restrict__ out)
{
  __shared__ __align__(16) float xbuf[2][2][II];   // [t&1][b][i], LN'd x
  __shared__ __align__(16) float h1buf[2][HH];     // [b][u]
  __shared__ __align__(16) float h2buf[2][HH];     // [b][u]
  __shared__ __align__(16) float pre[4 * HH][2];   // [gate_row][b]

  const int lane = threadIdx.x;
  const int b0 = blockIdx.x * 2;

  const int gq = lane >> 4;        // gate 0..3 (i,f,g,o)
  const int uu = lane & 15;
  const int rA = gq * HH + uu;     // owned gate rows
  const int rB = rA + 16;
  const int u_t = lane & 31;       // elementwise mapping: unit
  const int b_t = lane >> 5;       // elementwise mapping: batch (0/1)

  // ---- weights -> registers (208 VGPRs), once ----
  float wih0[2][II], whh0[2][HH], wih1[2][HH], whh1[2][HH];
  float bias0[2], bias1[2];
  #pragma unroll
  for (int h = 0; h < 2; ++h) {
    const int r = h ? rB : rA;
    {
      const float4* p = (const float4*)(Wih0g + r * II);
      #pragma unroll
      for (int q = 0; q < II / 4; ++q) {
        float4 v = p[q];
        wih0[h][q*4+0]=v.x; wih0[h][q*4+1]=v.y; wih0[h][q*4+2]=v.z; wih0[h][q*4+3]=v.w;
      }
    }
    {
      const float4* p = (const float4*)(Whh0g + r * HH);
      #pragma unroll
      for (int q = 0; q < HH / 4; ++q) {
        float4 v = p[q];
        whh0[h][q*4+0]=v.x; whh0[h][q*4+1]=v.y; whh0[h][q*4+2]=v.z; whh0[h][q*4+3]=v.w;
      }
    }
    {
      const float4* p = (const float4*)(Wih1g + r * HH);
      #pragma unroll
      for (int q = 0; q < HH / 4; ++q) {
        float4 v = p[q];
        wih1[h][q*4+0]=v.x; wih1[h][q*4+1]=v.y; wih1[h][q*4+2]=v.z; wih1[h][q*4+3]=v.w;
      }
    }
    {
      const float4* p = (const float4*)(Whh1g + r * HH);
      #pragma unroll
      for (int q = 0; q < HH / 4; ++q) {
        float4 v = p[q];
        whh1[h][q*4+0]=v.x; whh1[h][q*4+1]=v.y; whh1[h][q*4+2]=v.z; whh1[h][q*4+3]=v.w;
      }
    }
    bias0[h] = bih0[r] + bhh0[r];
    bias1[h] = bih1[r] + bhh1[r];
  }

  const float lngv = ln_g[lane & 7];
  const float lnbv = ln_b[lane & 7];

  h1buf[b_t][u_t] = 0.f;
  h2buf[b_t][u_t] = 0.f;
  float c1 = 0.f, c2 = 0.f;

  for (int t = 0; t < TT; ++t) {
    const int tt = t & 1;

    // ---- stage x for (t, t+1) on even t: full 64B line per batch, LN fused ----
    if (tt == 0 && lane < 32) {
      const int bb = lane >> 4, ts = (lane >> 3) & 1, ii = lane & 7;
      float v = X[(size_t)(b0 + bb) * (TT * II) + (size_t)(t + ts) * II + ii];
      float s = v;
      s += __shfl_xor(s, 1); s += __shfl_xor(s, 2); s += __shfl_xor(s, 4);
      const float mu = s * 0.125f;
      const float d = v - mu;
      float q2 = d * d;
      q2 += __shfl_xor(q2, 1); q2 += __shfl_xor(q2, 2); q2 += __shfl_xor(q2, 4);
      const float inv = __builtin_amdgcn_rsqf(fmaf(q2, 0.125f, 1e-5f)); // rsqrt(var+eps)
      xbuf[ts][bb][ii] = fmaf(d * inv, lngv, lnbv);
    }
    __syncthreads();  // S1 (single-wave: waitcnt only)

    // ---- layer 0 dot: gates[row,b] = b0r + Wih0*xn + Whh0*h1 ----
    float acc[2][2];
    acc[0][0] = bias0[0]; acc[0][1] = bias0[0];
    acc[1][0] = bias0[1]; acc[1][1] = bias0[1];
    #pragma unroll
    for (int b = 0; b < 2; ++b) {
      const float4* xp = (const float4*)&xbuf[tt][b][0];
      #pragma unroll
      for (int q = 0; q < II / 4; ++q) {
        const float4 v = xp[q];
        #pragma unroll
        for (int h = 0; h < 2; ++h) {
          acc[h][b] = fmaf(wih0[h][q*4+0], v.x, acc[h][b]);
          acc[h][b] = fmaf(wih0[h][q*4+1], v.y, acc[h][b]);
          acc[h][b] = fmaf(wih0[h][q*4+2], v.z, acc[h][b]);
          acc[h][b] = fmaf(wih0[h][q*4+3], v.w, acc[h][b]);
        }
      }
      const float4* hp = (const float4*)&h1buf[b][0];
      #pragma unroll
      for (int q = 0; q < HH / 4; ++q) {
        const float4 v = hp[q];
        #pragma unroll
        for (int h = 0; h < 2; ++h) {
          acc[h][b] = fmaf(whh0[h][q*4+0], v.x, acc[h][b]);
          acc[h][b] = fmaf(whh0[h][q*4+1], v.y, acc[h][b]);
          acc[h][b] = fmaf(whh0[h][q*4+2], v.z, acc[h][b]);
          acc[h][b] = fmaf(whh0[h][q*4+3], v.w, acc[h][b]);
        }
      }
    }
    *(float2*)&pre[rA][0] = make_float2(acc[0][0], acc[0][1]);
    *(float2*)&pre[rB][0] = make_float2(acc[1][0], acc[1][1]);
    __syncthreads();  // S2

    // ---- layer 0 elementwise: lane = (u_t, b_t) ----
    {
      const float pi = pre[u_t][b_t];
      const float pf = pre[HH + u_t][b_t];
      const float pg = pre[2 * HH + u_t][b_t];
      const float po = pre[3 * HH + u_t][b_t];
      const float gi = sigf_(pi), gf = sigf_(pf), gg = tanhf_(pg), go = sigf_(po);
      c1 = fmaf(gf, c1, gi * gg);
      h1buf[b_t][u_t] = go * tanhf_(c1);
    }
    __syncthreads();  // S3

    // ---- layer 1 dot: gates = b1r + Wih1*h1 + Whh1*h2 ----
    acc[0][0] = bias1[0]; acc[0][1] = bias1[0];
    acc[1][0] = bias1[1]; acc[1][1] = bias1[1];
    #pragma unroll
    for (int b = 0; b < 2; ++b) {
      const float4* hp1 = (const float4*)&h1buf[b][0];
      #pragma unroll
      for (int q = 0; q < HH / 4; ++q) {
        const float4 v = hp1[q];
        #pragma unroll
        for (int h = 0; h < 2; ++h) {
          acc[h][b] = fmaf(wih1[h][q*4+0], v.x, acc[h][b]);
          acc[h][b] = fmaf(wih1[h][q*4+1], v.y, acc[h][b]);
          acc[h][b] = fmaf(wih1[h][q*4+2], v.z, acc[h][b]);
          acc[h][b] = fmaf(wih1[h][q*4+3], v.w, acc[h][b]);
        }
      }
      const float4* hp2 = (const float4*)&h2buf[b][0];
      #pragma unroll
      for (int q = 0; q < HH / 4; ++q) {
        const float4 v = hp2[q];
        #pragma unroll
        for (int h = 0; h < 2; ++h) {
          acc[h][b] = fmaf(whh1[h][q*4+0], v.x, acc[h][b]);
          acc[h][b] = fmaf(whh1[h][q*4+1], v.y, acc[h][b]);
          acc[h][b] = fmaf(whh1[h][q*4+2], v.z, acc[h][b]);
          acc[h][b] = fmaf(whh1[h][q*4+3], v.w, acc[h][b]);
        }
      }
    }
    *(float2*)&pre[rA][0] = make_float2(acc[0][0], acc[0][1]);
    *(float2*)&pre[rB][0] = make_float2(acc[1][0], acc[1][1]);
    __syncthreads();  // S4

    // ---- layer 1 elementwise ----
    {
      const float pi = pre[u_t][b_t];
      const float pf = pre[HH + u_t][b_t];
      const float pg = pre[2 * HH + u_t][b_t];
      const float po = pre[3 * HH + u_t][b_t];
      const float gi = sigf_(pi), gf = sigf_(pf), gg = tanhf_(pg), go = sigf_(po);
      c2 = fmaf(gf, c2, gi * gg);
      h2buf[b_t][u_t] = go * tanhf_(c2);
    }
    // next iteration's S1/S2/S3 order the h2buf write vs. next layer-1 reads
  }
  __syncthreads();

  // ---- head: out[b] = tanh(W2 @ relu(W1 @ h2 + b1) + b2) ----
  if (lane < 32) {
    const int j = lane & 15;   // F1 = 16
    const int b = lane >> 4;
    float a = b1[j];
    const float4* hp = (const float4*)&h2buf[b][0];
    const float4* wp = (const float4*)(W1 + j * HH);
    #pragma unroll
    for (int q = 0; q < HH / 4; ++q) {
      const float4 hv = hp[q];
      const float4 wv = wp[q];
      a = fmaf(wv.x, hv.x, a); a = fmaf(wv.y, hv.y, a);
      a = fmaf(wv.z, hv.z, a); a = fmaf(wv.w, hv.w, a);
    }
    float r = fmaxf(a, 0.f) * W2[j];
    r += __shfl_xor(r, 1);
    r += __shfl_xor(r, 2);
    r += __shfl_xor(r, 4);
    r += __shfl_xor(r, 8);
    if (j == 0) out[b0 + b] = tanhf_(r + b2[0]);
  }
}

extern "C" void kernel_launch(void* const* d_in, const int* in_sizes, int n_in,
                              void* d_out, int out_size, void* d_ws, size_t ws_size,
                              hipStream_t stream) {
  const float* X     = (const float*)d_in[0];
  const float* ln_g  = (const float*)d_in[1];
  const float* ln_b  = (const float*)d_in[2];
  const float* Wih0g = (const float*)d_in[3];
  const float* Whh0g = (const float*)d_in[4];
  const float* bih0  = (const float*)d_in[5];
  const float* bhh0  = (const float*)d_in[6];
  const float* Wih1g = (const float*)d_in[7];
  const float* Whh1g = (const float*)d_in[8];
  const float* bih1  = (const float*)d_in[9];
  const float* bhh1  = (const float*)d_in[10];
  const float* W1    = (const float*)d_in[11];
  const float* b1    = (const float*)d_in[12];
  const float* W2    = (const float*)d_in[13];
  const float* b2    = (const float*)d_in[14];
  float* out = (float*)d_out;

  const int Bn = in_sizes[0] / (TT * II);   // 8192
  dim3 grid(Bn / 2), block(64);
  hipLaunchKernelGGL(lstm_fused, grid, block, 0, stream,
                     X, ln_g, ln_b, Wih0g, Whh0g, bih0, bhh0,
                     Wih1g, Whh1g, bih1, bhh1, W1, b1, W2, b2, out);
}